// Round 5
// baseline (299.907 us; speedup 1.0000x reference)
//
#include <hip/hip_runtime.h>

#define HDIM 128

typedef __bf16 bf16_t;
typedef bf16_t bf16x8 __attribute__((ext_vector_type(8)));
typedef float  f32x4  __attribute__((ext_vector_type(4)));

__device__ __forceinline__ unsigned short f2bf_rne(float f) {
    unsigned int u = __float_as_uint(f);
    u += 0x7fffu + ((u >> 16) & 1u);   // round-to-nearest-even
    return (unsigned short)(u >> 16);
}
__device__ __forceinline__ unsigned int pk_bf2(float a, float b) {
    return (unsigned int)f2bf_rne(a) | ((unsigned int)f2bf_rne(b) << 16);
}

// W1 [2*128 k][128 n] fp32 -> Wt [2][n=128][k=128] bf16 (n-major, k-contiguous)
__global__ __launch_bounds__(256) void convert_w1(
    const float* __restrict__ W1, unsigned short* __restrict__ Wt)
{
    const int o = blockIdx.x * 256 + threadIdx.x;     // 0..32767
    const int g = o >> 14, rem = o & 16383, n = rem >> 7, k = rem & 127;
    Wt[o] = f2bf_rne(W1[g * 16384 + k * 128 + n]);
}

// C_bf16[M,128] = bf16(Z[M,128]) @ bf16(W[128,128]) (+ b1 if second half).
// v7: amortize per-block fixed costs (W-stage, barrier, launch) 4x vs v6:
//  - 256 rows per block (4 subtiles of 64), 782 blocks total (vs 3126).
//  - W staged ONCE per block, XOR-swizzled chunks (T2), single barrier.
//  - 2-deep Z register pipeline: issue subtile t+1 loads, then pack+MFMA+
//    store subtile t. FIFO vmcnt: pack(t) waits only on older loads, so
//    next-tile loads stay in flight across the compute. ~145 VGPR.
__global__ __launch_bounds__(256) void node_gemm_v7(
    const float* __restrict__ Zs, const float* __restrict__ Zd,
    const unsigned short* __restrict__ Wt, const float* __restrict__ b1,
    unsigned short* __restrict__ Abuf, unsigned short* __restrict__ Bbuf,
    int M, int blocks_per_half)
{
    __shared__ unsigned short wlds[128 * 128];   // 32 KB

    const bool second = (blockIdx.x >= blocks_per_half);
    const int blk = second ? (blockIdx.x - blocks_per_half) : blockIdx.x;
    const float* __restrict__ Z          = second ? Zd : Zs;
    const unsigned short* __restrict__ W = Wt + (second ? 128 * 128 : 0);
    unsigned short* __restrict__ C       = second ? Bbuf : Abuf;
    const int t    = threadIdx.x;
    const int lane = t & 63;
    const int wave = t >> 6;
    const int m    = lane & 15;     // Z row within wave's 16 / D col group
    const int quad = lane >> 4;

    // ---- stage W first (L2-hot, ~300cy) so ds_writes don't queue behind
    //      HBM Z loads in the FIFO vmcnt order ----
    #pragma unroll
    for (int j = 0; j < 8; ++j) {
        const int u = t + 256 * j;          // 0..2047
        const int n = u >> 4, cc = u & 15;
        const uint4 v = *reinterpret_cast<const uint4*>(W + n * 128 + cc * 8);
        *reinterpret_cast<uint4*>(wlds + n * 128 + (cc ^ (n & 7)) * 8) = v;
    }
    __syncthreads();

    const int row_base = blk * 256 + wave * 16 + m;

    // ---- Z pipeline buffers (2-deep) ----
    float4 zv[2][4][2];

    // prologue: issue subtile 0 loads
    {
        const int r  = row_base;                       // t=0
        const int rc = (r < M) ? r : (M - 1);
        const float* zrow = Z + (size_t)rc * HDIM;
        #pragma unroll
        for (int ks = 0; ks < 4; ++ks) {
            zv[0][ks][0] = *reinterpret_cast<const float4*>(zrow + ks * 32 + quad * 8);
            zv[0][ks][1] = *reinterpret_cast<const float4*>(zrow + ks * 32 + quad * 8 + 4);
        }
    }

    #pragma unroll
    for (int st = 0; st < 4; ++st) {
        const int cur = st & 1;

        // issue next subtile's Z loads (hide HBM latency under MFMA+store)
        if (st < 3) {
            const int rn  = row_base + (st + 1) * 64;
            const int rnc = (rn < M) ? rn : (M - 1);
            const float* zrow = Z + (size_t)rnc * HDIM;
            #pragma unroll
            for (int ks = 0; ks < 4; ++ks) {
                zv[cur ^ 1][ks][0] = *reinterpret_cast<const float4*>(zrow + ks * 32 + quad * 8);
                zv[cur ^ 1][ks][1] = *reinterpret_cast<const float4*>(zrow + ks * 32 + quad * 8 + 4);
            }
        }

        // pack current subtile to bf16 fragments
        union { unsigned int u[4]; bf16x8 h; } zf[4];
        #pragma unroll
        for (int ks = 0; ks < 4; ++ks) {
            zf[ks].u[0] = pk_bf2(zv[cur][ks][0].x, zv[cur][ks][0].y);
            zf[ks].u[1] = pk_bf2(zv[cur][ks][0].z, zv[cur][ks][0].w);
            zf[ks].u[2] = pk_bf2(zv[cur][ks][1].x, zv[cur][ks][1].y);
            zf[ks].u[3] = pk_bf2(zv[cur][ks][1].z, zv[cur][ks][1].w);
        }

        // MFMA: acc[ct] += W[ct*16+m, ks*32..] * z
        f32x4 acc[8] = {};
        #pragma unroll
        for (int ks = 0; ks < 4; ++ks) {
            const int cidx = (ks * 4 + quad) ^ (m & 7);   // swizzled 16B-chunk
            #pragma unroll
            for (int ct = 0; ct < 8; ++ct) {
                const bf16x8 wf = *reinterpret_cast<const bf16x8*>(
                    wlds + (ct * 16 + m) * 128 + cidx * 8);
                acc[ct] = __builtin_amdgcn_mfma_f32_16x16x32_bf16(
                    wf, zf[ks].h, acc[ct], 0, 0, 0);
            }
        }

        // epilogue: +bias, fp32->bf16, 8-B stores
        const int r = row_base + st * 64;
        if (r < M) {
            unsigned short* crow = C + (size_t)r * HDIM;
            #pragma unroll
            for (int ct = 0; ct < 8; ++ct) {
                const int col = ct * 16 + quad * 4;
                float4 bv = make_float4(0.f, 0.f, 0.f, 0.f);
                if (second) bv = *reinterpret_cast<const float4*>(b1 + col);
                uint2 o;
                o.x = pk_bf2(acc[ct][0] + bv.x, acc[ct][1] + bv.y);
                o.y = pk_bf2(acc[ct][2] + bv.z, acc[ct][3] + bv.w);
                *reinterpret_cast<uint2*>(crow + col) = o;
            }
        }
    }
}

// out[e] = relu(A[row[e]] + B[col[e]]) . W2 + b2, A/B bf16 (b1 folded into B).
// 16 lanes per edge; lane handles 8 features (16 B load/operand).
// Unchanged: measured at the 3.46 TB/s random-gather wall (R2 MLP null).
__global__ __launch_bounds__(256) void edge_decode_bf16(
    const unsigned short* __restrict__ A, const unsigned short* __restrict__ Bm,
    const int* __restrict__ idx,   // [2*E]: rows then cols
    const float* __restrict__ W2, const float* __restrict__ b2,
    float* __restrict__ out, int E)
{
    const int t   = threadIdx.x;
    const int sub = t & 15;
    const int grp = t >> 4;

    float w2r[8];
    #pragma unroll
    for (int i = 0; i < 8; ++i) w2r[i] = W2[sub * 8 + i];
    const float b2s = b2[0];

    const int stride = gridDim.x * 16;
    for (int e = blockIdx.x * 16 + grp; e < E; e += stride) {
        const int r = idx[e];
        const int c = idx[E + e];
        const uint4 av = *reinterpret_cast<const uint4*>(A  + (size_t)r * HDIM + sub * 8);
        const uint4 bv = *reinterpret_cast<const uint4*>(Bm + (size_t)c * HDIM + sub * 8);

        float s = 0.f;
        #pragma unroll
        for (int i = 0; i < 4; ++i) {
            const unsigned int ua = (&av.x)[i];
            const unsigned int ub = (&bv.x)[i];
            s += fmaxf(__uint_as_float(ua << 16)         + __uint_as_float(ub << 16),         0.f) * w2r[2 * i];
            s += fmaxf(__uint_as_float(ua & 0xffff0000u) + __uint_as_float(ub & 0xffff0000u), 0.f) * w2r[2 * i + 1];
        }
        s += __shfl_xor(s, 1);
        s += __shfl_xor(s, 2);
        s += __shfl_xor(s, 4);
        s += __shfl_xor(s, 8);
        if (sub == 0) out[e] = s + b2s;
    }
}

extern "C" void kernel_launch(void* const* d_in, const int* in_sizes, int n_in,
                              void* d_out, int out_size, void* d_ws, size_t ws_size,
                              hipStream_t stream)
{
    const float* z_src = (const float*)d_in[0];
    const float* z_dst = (const float*)d_in[1];
    const int*   eidx  = (const int*)d_in[2];
    const float* W1    = (const float*)d_in[3];
    const float* b1    = (const float*)d_in[4];
    const float* W2    = (const float*)d_in[5];
    const float* b2    = (const float*)d_in[6];
    float*       outp  = (float*)d_out;

    const int Nn = in_sizes[0] / HDIM;    // 100000
    const int E  = in_sizes[2] / 2;       // 2000000

    unsigned short* Abuf = (unsigned short*)d_ws;
    unsigned short* Bbuf = Abuf + (size_t)Nn * HDIM;
    unsigned short* Wt   = Bbuf + (size_t)Nn * HDIM;

    convert_w1<<<128, 256, 0, stream>>>(W1, Wt);

    const int bph = (Nn + 255) >> 8;      // 391 blocks per half (256 rows each)
    node_gemm_v7<<<2 * bph, 256, 0, stream>>>(
        z_src, z_dst, Wt, b1, Abuf, Bbuf, Nn, bph);

    edge_decode_bf16<<<8192, 256, 0, stream>>>(Abuf, Bbuf, eidx, W2, b2, outp, E);
}